// Round 5
// baseline (93.311 us; speedup 1.0000x reference)
//
#include <hip/hip_runtime.h>

#define Cnum 20
#define NCH  30             // 2*5 + 20
#define NCONF 98
#define IMGF 1470           // 49*30 floats per image
#define IPB  8              // images per block (one wave each)
#define NTHREADS 512
#define LCf 5.0f
#define LNf 0.5f

__global__ __launch_bounds__(NTHREADS) void yolo_loss_kernel(
    const float* __restrict__ outputs,
    const float* __restrict__ boxes,
    const int*   __restrict__ labels,
    float*       __restrict__ block_sum,
    int*         __restrict__ counter,
    float*       __restrict__ out,
    int nb, int N)
{
    const int tid  = threadIdx.x;
    const int wave = tid >> 6;
    const int lane = tid & 63;
    const int n0   = blockIdx.x * IPB;

    __shared__ float  s_all[IPB * IMGF];   // 47040 B
    __shared__ float  s_ns[IPB];
    __shared__ float  s_tri[IPB][3];       // {tl, marked_sum, marked_cnt}
    __shared__ float  s_red[IPB];
    __shared__ double s_dd[8];
    __shared__ int    s_last;

    // ---- stage 8 images straight into LDS: 2940 float4 via width-16 global_load_lds ----
    const float* gsrc = outputs + (size_t)n0 * IMGF;
    #pragma unroll
    for (int k = 0; k < 6; ++k) {
        int j = tid + k * NTHREADS;                  // float4 index
        if (j < (IPB * IMGF) / 4) {                  // 2940
            __builtin_amdgcn_global_load_lds(
                (const __attribute__((address_space(1))) void*)(gsrc + (size_t)j * 4),
                (__attribute__((address_space(3))) void*)((char*)s_all + (size_t)(k * NTHREADS + wave * 64) * 16),
                16, 0, 0);
        }
    }

    // hoist target-data loads above the barrier (latency hides under staging drain)
    float4 bx = make_float4(0.f, 0.f, 0.f, 0.f);
    int lab = 0;
    if (wave < 2) {
        bx  = reinterpret_cast<const float4*>(boxes)[(size_t)n0 * 16 + wave * 64 + lane];
        lab = labels[(size_t)n0 * 16 + wave * 64 + lane] - 1;
    }
    __syncthreads();

    // ---- every wave: sum ALL 98 conf^2 of its own image (mask-free) ----
    {
        const float* simg = s_all + wave * IMGF;
        int c = lane >> 1, b = lane & 1;             // slots 0..63
        float cf = simg[c * NCH + b * 5 + 4];
        float ns = cf * cf;
        int s2 = lane + 64;                          // slots 64..97
        if (s2 < NCONF) {
            c = s2 >> 1; b = s2 & 1;
            cf = simg[c * NCH + b * 5 + 4];
            ns += cf * cf;
        }
        #pragma unroll
        for (int off = 32; off > 0; off >>= 1) ns += __shfl_xor(ns, off);
        if (lane == 0) s_ns[wave] = ns;
    }

    // ---- waves 0,1: 64 targets each (4 images x 16 lanes), all lanes active ----
    if (wave < 2) {
        const int img   = wave * 4 + (lane >> 4);
        const int myidx = lane & 15;
        const int gbase = lane & 48;
        const float* simg = s_all + img * IMGF;

        float tx = bx.x, ty = bx.y, tw = bx.z, th = bx.w;
        float fx = tx * 7.0f, fy = ty * 7.0f;
        int gxi = (int)fx, gyi = (int)fy;
        float offx = fx - (float)gxi;
        float offy = fy - (float)gyi;

        const float* cell = simg + (gyi * 7 + gxi) * NCH;

        float x1a = tx - tw * 0.5f, y1a = ty - th * 0.5f;
        float x2a = tx + tw * 0.5f, y2a = ty + th * 0.5f;
        float areaA = tw * th;

        float ious[2], pxv[2], pyv[2], pwv[2], phv[2], cfv[2];
        #pragma unroll
        for (int b = 0; b < 2; ++b) {
            float rx = cell[b * 5 + 0], ry = cell[b * 5 + 1];
            float pw = cell[b * 5 + 2], ph = cell[b * 5 + 3];
            float px = (rx + (float)gxi) * (1.0f / 7.0f);
            float py = (ry + (float)gyi) * (1.0f / 7.0f);
            pxv[b] = px; pyv[b] = py; pwv[b] = pw; phv[b] = ph;
            cfv[b] = cell[b * 5 + 4];

            float x1b = px - pw * 0.5f, y1b = py - ph * 0.5f;
            float x2b = px + pw * 0.5f, y2b = py + ph * 0.5f;
            float iw = fmaxf(fminf(x2a, x2b) - fmaxf(x1a, x1b), 0.0f);
            float ih = fmaxf(fminf(y2a, y2b) - fmaxf(y1a, y1b), 0.0f);
            float inter = iw * ih;
            float uni = areaA + pw * ph - inter;
            ious[b] = inter / fmaxf(uni, 1e-10f);
        }
        int best = (ious[1] >= ious[0]) ? 1 : 0;     // ties -> last box (ref semantics)

        // in-register distinct-marked-slot bookkeeping (replaces s_mask)
        int s = (gyi * 7 + gxi) * 2 + best;
        float cfm = best ? cfv[1] : cfv[0];
        bool first = true;
        #pragma unroll
        for (int j = 0; j < 15; ++j) {
            int sj = __shfl(s, gbase + j);
            if (j < myidx && sj == s) first = false;
        }
        float msum = first ? cfm * cfm : 0.0f;
        float mcnt = first ? 1.0f : 0.0f;

        const float eps = 1e-6f;
        float dx = (best ? pxv[1] : pxv[0]) - offx;
        float dy = (best ? pyv[1] : pyv[0]) - offy;
        float bw = best ? pwv[1] : pwv[0];
        float bh = best ? phv[1] : phv[0];
        float dw = sqrtf(fmaxf(bw, eps)) - sqrtf(fmaxf(tw, eps));
        float dh = sqrtf(fmaxf(bh, eps)) - sqrtf(fmaxf(th, eps));
        float box_l = dx * dx + dy * dy + dw * dw + dh * dh;
        float obj_l = (cfm - 1.0f) * (cfm - 1.0f);

        // class loss via sum-of-squares identity: one reciprocal, no ev[] array
        const float* cl = cell + 10;
        float m = cl[0];
        #pragma unroll
        for (int c = 1; c < Cnum; ++c) m = fmaxf(m, cl[c]);
        float esum = 0.0f, e2 = 0.0f, elab = 0.0f;
        #pragma unroll
        for (int c = 0; c < Cnum; ++c) {
            float e = __expf(cl[c] - m);
            esum += e; e2 += e * e;
            if (c == lab) elab = e;
        }
        float inv = 1.0f / esum;
        float cls_l = e2 * inv * inv - 2.0f * elab * inv + 1.0f;

        float tl = LCf * box_l + obj_l + cls_l;

        // 16-lane group reduce (per image)
        #pragma unroll
        for (int off = 1; off < 16; off <<= 1) {
            tl   += __shfl_xor(tl, off);
            msum += __shfl_xor(msum, off);
            mcnt += __shfl_xor(mcnt, off);
        }
        if (myidx == 0) {
            s_tri[img][0] = tl;
            s_tri[img][1] = msum;
            s_tri[img][2] = mcnt;
        }
    }
    __syncthreads();

    if (tid < IPB) {
        s_red[tid] = s_tri[tid][0]
                   + LNf * (s_ns[tid] - s_tri[tid][1]) / (98.0f - s_tri[tid][2]);
    }
    __syncthreads();

    if (tid == 0) {
        float bs = 0.0f;
        #pragma unroll
        for (int i = 0; i < IPB; ++i) bs += s_red[i];
        __hip_atomic_store(&block_sum[blockIdx.x], bs,
                           __ATOMIC_RELEASE, __HIP_MEMORY_SCOPE_AGENT);
        int old = __hip_atomic_fetch_add(counter, 1,
                                         __ATOMIC_ACQ_REL, __HIP_MEMORY_SCOPE_AGENT);
        s_last = (old == nb - 1) ? 1 : 0;
    }
    __syncthreads();

    // ---- last block: deterministic fixed-order final reduction ----
    if (s_last) {
        double acc = 0.0;
        for (int i = tid; i < nb; i += NTHREADS)
            acc += (double)__hip_atomic_load(&block_sum[i],
                                             __ATOMIC_ACQUIRE, __HIP_MEMORY_SCOPE_AGENT);
        #pragma unroll
        for (int off = 32; off > 0; off >>= 1) acc += __shfl_xor(acc, off);
        if (lane == 0) s_dd[wave] = acc;
        __syncthreads();
        if (tid == 0) {
            double t = 0.0;
            #pragma unroll
            for (int w = 0; w < 8; ++w) t += s_dd[w];
            out[0] = (float)(t / (double)N);
        }
    }
}

extern "C" void kernel_launch(void* const* d_in, const int* in_sizes, int n_in,
                              void* d_out, int out_size, void* d_ws, size_t ws_size,
                              hipStream_t stream) {
    const float* outputs = (const float*)d_in[0];
    const float* boxes   = (const float*)d_in[1];
    const int*   labels  = (const int*)d_in[2];
    float* out = (float*)d_out;

    const int N  = in_sizes[0] / IMGF;  // 16384
    const int nb = N / IPB;             // 2048 blocks
    float* block_sum = (float*)d_ws;
    int*   counter   = (int*)((char*)d_ws + (size_t)nb * sizeof(float));

    hipMemsetAsync(counter, 0, sizeof(int), stream); // replay-safe counter reset
    yolo_loss_kernel<<<nb, NTHREADS, 0, stream>>>(outputs, boxes, labels,
                                                  block_sum, counter, out, nb, N);
}

// Round 6
// 68.646 us; speedup vs baseline: 1.3593x; 1.3593x over previous
//
#include <hip/hip_runtime.h>

#define Cnum 20
#define NCH  30             // 2*5 + 20
#define NCONF 98
#define IMGF 1470           // 49*30 floats per image
#define IPB  4              // images per block (one wave each)
#define LCf 5.0f
#define LNf 0.5f

__global__ __launch_bounds__(256) void yolo_loss_kernel(
    const float* __restrict__ outputs,
    const float* __restrict__ boxes,
    const int*   __restrict__ labels,
    float*       __restrict__ out,
    float invN)
{
    const int tid  = threadIdx.x;
    const int wave = tid >> 6;
    const int lane = tid & 63;
    const int n0   = blockIdx.x * IPB;

    __shared__ float s_all[IPB * IMGF];  // 23520 B
    __shared__ float s_ns[IPB];
    __shared__ float s_tri[IPB][3];      // {tl, marked_sum, marked_cnt}
    __shared__ float s_pb[IPB];

    // ---- stage 4 images straight into LDS: 1470 float4 via width-16 global_load_lds ----
    const float* gsrc = outputs + (size_t)n0 * IMGF;
    #pragma unroll
    for (int k = 0; k < 6; ++k) {
        int j = tid + k * 256;                       // float4 index
        if (j < (IPB * IMGF) / 4) {                  // 1470
            __builtin_amdgcn_global_load_lds(
                (const __attribute__((address_space(1))) void*)(gsrc + (size_t)j * 4),
                (__attribute__((address_space(3))) void*)((char*)s_all + (size_t)(k * 256 + wave * 64) * 16),
                16, 0, 0);
        }
    }

    // hoist target-data loads above the barrier (latency hides under staging drain)
    float4 bx = make_float4(0.f, 0.f, 0.f, 0.f);
    int lab = 0;
    if (wave == 0) {
        bx  = reinterpret_cast<const float4*>(boxes)[(size_t)n0 * 16 + lane];
        lab = labels[(size_t)n0 * 16 + lane] - 1;
    }
    __syncthreads();

    // ---- every wave: sum ALL 98 conf^2 of its own image (mask-free) ----
    {
        const float* simg = s_all + wave * IMGF;
        int c = lane >> 1, b = lane & 1;             // slots 0..63
        float cf = simg[c * NCH + b * 5 + 4];
        float ns = cf * cf;
        int s2 = lane + 64;                          // slots 64..97
        if (s2 < NCONF) {
            c = s2 >> 1; b = s2 & 1;
            cf = simg[c * NCH + b * 5 + 4];
            ns += cf * cf;
        }
        #pragma unroll
        for (int off = 32; off > 0; off >>= 1) ns += __shfl_xor(ns, off);
        if (lane == 0) s_ns[wave] = ns;
    }

    // ---- wave 0: all 64 targets (4 images x 16 lanes), all lanes active ----
    if (wave == 0) {
        const int img   = lane >> 4;
        const int myidx = lane & 15;
        const int gbase = lane & 48;
        const float* simg = s_all + img * IMGF;

        float tx = bx.x, ty = bx.y, tw = bx.z, th = bx.w;
        float fx = tx * 7.0f, fy = ty * 7.0f;
        int gxi = (int)fx, gyi = (int)fy;
        float offx = fx - (float)gxi;
        float offy = fy - (float)gyi;

        const float* cell = simg + (gyi * 7 + gxi) * NCH;

        float x1a = tx - tw * 0.5f, y1a = ty - th * 0.5f;
        float x2a = tx + tw * 0.5f, y2a = ty + th * 0.5f;
        float areaA = tw * th;

        float ious[2], pxv[2], pyv[2], pwv[2], phv[2], cfv[2];
        #pragma unroll
        for (int b = 0; b < 2; ++b) {
            float rx = cell[b * 5 + 0], ry = cell[b * 5 + 1];
            float pw = cell[b * 5 + 2], ph = cell[b * 5 + 3];
            float px = (rx + (float)gxi) * (1.0f / 7.0f);
            float py = (ry + (float)gyi) * (1.0f / 7.0f);
            pxv[b] = px; pyv[b] = py; pwv[b] = pw; phv[b] = ph;
            cfv[b] = cell[b * 5 + 4];

            float x1b = px - pw * 0.5f, y1b = py - ph * 0.5f;
            float x2b = px + pw * 0.5f, y2b = py + ph * 0.5f;
            float iw = fmaxf(fminf(x2a, x2b) - fmaxf(x1a, x1b), 0.0f);
            float ih = fmaxf(fminf(y2a, y2b) - fmaxf(y1a, y1b), 0.0f);
            float inter = iw * ih;
            float uni = areaA + pw * ph - inter;
            ious[b] = inter / fmaxf(uni, 1e-10f);
        }
        int best = (ious[1] >= ious[0]) ? 1 : 0;     // ties -> last box (ref semantics)

        // in-register distinct-marked-slot bookkeeping (replaces s_mask)
        int s = (gyi * 7 + gxi) * 2 + best;
        float cfm = best ? cfv[1] : cfv[0];
        bool first = true;
        #pragma unroll
        for (int j = 0; j < 15; ++j) {
            int sj = __shfl(s, gbase + j);
            if (j < myidx && sj == s) first = false;
        }
        float msum = first ? cfm * cfm : 0.0f;
        float mcnt = first ? 1.0f : 0.0f;

        const float eps = 1e-6f;
        float dx = (best ? pxv[1] : pxv[0]) - offx;
        float dy = (best ? pyv[1] : pyv[0]) - offy;
        float bw = best ? pwv[1] : pwv[0];
        float bh = best ? phv[1] : phv[0];
        float dw = sqrtf(fmaxf(bw, eps)) - sqrtf(fmaxf(tw, eps));
        float dh = sqrtf(fmaxf(bh, eps)) - sqrtf(fmaxf(th, eps));
        float box_l = dx * dx + dy * dy + dw * dw + dh * dh;
        float obj_l = (cfm - 1.0f) * (cfm - 1.0f);

        // class loss via sum-of-squares identity: one reciprocal, no ev[] array
        const float* cl = cell + 10;
        float m = cl[0];
        #pragma unroll
        for (int c = 1; c < Cnum; ++c) m = fmaxf(m, cl[c]);
        float esum = 0.0f, e2 = 0.0f, elab = 0.0f;
        #pragma unroll
        for (int c = 0; c < Cnum; ++c) {
            float e = __expf(cl[c] - m);
            esum += e; e2 += e * e;
            if (c == lab) elab = e;
        }
        float inv = 1.0f / esum;
        float cls_l = e2 * inv * inv - 2.0f * elab * inv + 1.0f;

        float tl = LCf * box_l + obj_l + cls_l;

        // 16-lane group reduce (per image)
        #pragma unroll
        for (int off = 1; off < 16; off <<= 1) {
            tl   += __shfl_xor(tl, off);
            msum += __shfl_xor(msum, off);
            mcnt += __shfl_xor(mcnt, off);
        }
        if (myidx == 0) {
            s_tri[img][0] = tl;
            s_tri[img][1] = msum;
            s_tri[img][2] = mcnt;
        }
    }
    __syncthreads();

    if (tid < IPB) {
        s_pb[tid] = s_tri[tid][0]
                  + LNf * (s_ns[tid] - s_tri[tid][1]) / (98.0f - s_tri[tid][2]);
    }
    __syncthreads();

    // relaxed device-scope atomic (plain atomicAdd): no L2 wb/inv, no fences
    if (tid == 0) {
        float bs = (s_pb[0] + s_pb[1]) + (s_pb[2] + s_pb[3]);
        atomicAdd(out, bs * invN);
    }
}

extern "C" void kernel_launch(void* const* d_in, const int* in_sizes, int n_in,
                              void* d_out, int out_size, void* d_ws, size_t ws_size,
                              hipStream_t stream) {
    const float* outputs = (const float*)d_in[0];
    const float* boxes   = (const float*)d_in[1];
    const int*   labels  = (const int*)d_in[2];
    float* out = (float*)d_out;

    const int N  = in_sizes[0] / IMGF;  // 16384
    const int nb = N / IPB;             // 4096 blocks

    hipMemsetAsync(out, 0, sizeof(float), stream);  // replay-safe accumulator reset
    yolo_loss_kernel<<<nb, 256, 0, stream>>>(outputs, boxes, labels, out,
                                             1.0f / (float)N);
}

// Round 7
// 30.168 us; speedup vs baseline: 3.0931x; 2.2755x over previous
//
#include <hip/hip_runtime.h>

#define Cnum 20
#define NCH  30             // 2*5 + 20
#define NCONF 98
#define IMGF 1470           // floats per image
#define IPB  4              // images per group
#define GRPF (IPB*IMGF)     // 5880 floats per group
#define GRP4 1470           // float4 per group
#define PAD4 1536           // padded float4 per LDS buffer (uniform 6 loads/thread)
#define NB   1024           // persistent blocks
#define LCf 5.0f
#define LNf 0.5f

__device__ __forceinline__ void stage_group(const float* __restrict__ gsrc,
                                            float* s_base, int tid, int wave) {
    // 6 uniform global_load_lds per thread (wrap-clamped tail) -> vmcnt math is
    // identical in every wave. LDS dest = wave-uniform base + lane*16 (HW rule).
    #pragma unroll
    for (int k = 0; k < 6; ++k) {
        int j  = tid + k * 256;
        int je = (j < GRP4) ? j : (j - GRP4);   // pad lanes re-read group start
        __builtin_amdgcn_global_load_lds(
            (const __attribute__((address_space(1))) void*)(gsrc + (size_t)je * 4),
            (__attribute__((address_space(3))) void*)((char*)s_base + (size_t)(k * 256 + wave * 64) * 16),
            16, 0, 0);
    }
}

// Per-group math. All waves: conf^2 sum of own image. Wave 0: all 64 targets.
// Contains ONE raw barrier (s_ns visibility). Returns group total (wave 0 lanes).
__device__ __forceinline__ float compute_group(const float* __restrict__ sgrp,
                                               float* __restrict__ s_ns,
                                               float4 bx, int lab,
                                               int wave, int lane)
{
    // ---- ns: sum all 98 conf^2 of this wave's image ----
    {
        const float* simg = sgrp + wave * IMGF;
        int c = lane >> 1, b = lane & 1;
        float cf = simg[c * NCH + b * 5 + 4];
        float ns = cf * cf;
        int s2 = lane + 64;
        if (s2 < NCONF) {
            int c2 = s2 >> 1, b2 = s2 & 1;
            float cf2 = simg[c2 * NCH + b2 * 5 + 4];
            ns += cf2 * cf2;
        }
        #pragma unroll
        for (int off = 32; off > 0; off >>= 1) ns += __shfl_xor(ns, off);
        if (lane == 0) s_ns[wave] = ns;
    }
    // raw barrier (keeps staging vmcnt in flight): lgkm drain only
    asm volatile("s_waitcnt lgkmcnt(0)" ::: "memory");
    __builtin_amdgcn_sched_barrier(0);
    __builtin_amdgcn_s_barrier();
    __builtin_amdgcn_sched_barrier(0);

    float ret = 0.0f;
    if (wave == 0) {
        const int img   = lane >> 4;
        const int myidx = lane & 15;
        const int gbase = lane & 48;
        const float* simg = sgrp + img * IMGF;

        float tx = bx.x, ty = bx.y, tw = bx.z, th = bx.w;
        float fx = tx * 7.0f, fy = ty * 7.0f;
        int gxi = (int)fx, gyi = (int)fy;
        float offx = fx - (float)gxi;
        float offy = fy - (float)gyi;

        const float* cell = simg + (gyi * 7 + gxi) * NCH;

        float x1a = tx - tw * 0.5f, y1a = ty - th * 0.5f;
        float x2a = tx + tw * 0.5f, y2a = ty + th * 0.5f;
        float areaA = tw * th;

        float ious[2], pxv[2], pyv[2], pwv[2], phv[2], cfv[2];
        #pragma unroll
        for (int b = 0; b < 2; ++b) {
            float rx = cell[b * 5 + 0], ry = cell[b * 5 + 1];
            float pw = cell[b * 5 + 2], ph = cell[b * 5 + 3];
            float px = (rx + (float)gxi) * (1.0f / 7.0f);
            float py = (ry + (float)gyi) * (1.0f / 7.0f);
            pxv[b] = px; pyv[b] = py; pwv[b] = pw; phv[b] = ph;
            cfv[b] = cell[b * 5 + 4];

            float x1b = px - pw * 0.5f, y1b = py - ph * 0.5f;
            float x2b = px + pw * 0.5f, y2b = py + ph * 0.5f;
            float iw = fmaxf(fminf(x2a, x2b) - fmaxf(x1a, x1b), 0.0f);
            float ih = fmaxf(fminf(y2a, y2b) - fmaxf(y1a, y1b), 0.0f);
            float inter = iw * ih;
            float uni = areaA + pw * ph - inter;
            ious[b] = inter / fmaxf(uni, 1e-10f);
        }
        int best = (ious[1] >= ious[0]) ? 1 : 0;   // ties -> last box (ref)

        // distinct-marked-slot bookkeeping in-register
        int s = (gyi * 7 + gxi) * 2 + best;
        float cfm = best ? cfv[1] : cfv[0];
        bool first = true;
        #pragma unroll
        for (int j = 0; j < 15; ++j) {
            int sj = __shfl(s, gbase + j);
            if (j < myidx && sj == s) first = false;
        }
        float msum = first ? cfm * cfm : 0.0f;
        float mcnt = first ? 1.0f : 0.0f;

        const float eps = 1e-6f;
        float dx = (best ? pxv[1] : pxv[0]) - offx;
        float dy = (best ? pyv[1] : pyv[0]) - offy;
        float bw = best ? pwv[1] : pwv[0];
        float bh = best ? phv[1] : phv[0];
        float dw = sqrtf(fmaxf(bw, eps)) - sqrtf(fmaxf(tw, eps));
        float dh = sqrtf(fmaxf(bh, eps)) - sqrtf(fmaxf(th, eps));
        float box_l = dx * dx + dy * dy + dw * dw + dh * dh;
        float obj_l = (cfm - 1.0f) * (cfm - 1.0f);

        // class loss: sum-of-squares identity, one reciprocal
        const float* cl = cell + 10;
        float m = cl[0];
        #pragma unroll
        for (int c = 1; c < Cnum; ++c) m = fmaxf(m, cl[c]);
        float esum = 0.0f, e2 = 0.0f, elab = 0.0f;
        #pragma unroll
        for (int c = 0; c < Cnum; ++c) {
            float e = __expf(cl[c] - m);
            esum += e; e2 += e * e;
            if (c == lab) elab = e;
        }
        float inv = 1.0f / esum;
        float cls_l = e2 * inv * inv - 2.0f * elab * inv + 1.0f;

        float tl = LCf * box_l + obj_l + cls_l;

        // 16-lane group reduce -> every lane holds its image's sums
        #pragma unroll
        for (int off = 1; off < 16; off <<= 1) {
            tl   += __shfl_xor(tl, off);
            msum += __shfl_xor(msum, off);
            mcnt += __shfl_xor(mcnt, off);
        }
        float nsv = s_ns[img];
        float total = tl + LNf * (nsv - msum) / (98.0f - mcnt);
        total += __shfl_xor(total, 16);
        total += __shfl_xor(total, 32);   // sum of 4 images, all lanes
        ret = total;
    }
    return ret;
}

#define WAIT_VM8() do { asm volatile("s_waitcnt vmcnt(8)" ::: "memory"); \
    __builtin_amdgcn_sched_barrier(0); __builtin_amdgcn_s_barrier(); \
    __builtin_amdgcn_sched_barrier(0); } while (0)
#define WAIT_VM0() do { asm volatile("s_waitcnt vmcnt(0)" ::: "memory"); \
    __builtin_amdgcn_sched_barrier(0); __builtin_amdgcn_s_barrier(); \
    __builtin_amdgcn_sched_barrier(0); } while (0)
#define END_BAR() do { __builtin_amdgcn_sched_barrier(0); \
    __builtin_amdgcn_s_barrier(); __builtin_amdgcn_sched_barrier(0); } while (0)

__global__ __launch_bounds__(256) void yolo_loss_kernel(
    const float* __restrict__ outputs,
    const float* __restrict__ boxes,
    const int*   __restrict__ labels,
    float*       __restrict__ block_sum)
{
    const int tid  = threadIdx.x;
    const int wave = tid >> 6;
    const int lane = tid & 63;
    const int bid  = blockIdx.x;

    __shared__ float s_buf[2][PAD4 * 4];   // 2 x 24576 B
    __shared__ float s_ns[IPB];

    const float4* bx4 = reinterpret_cast<const float4*>(boxes);

    const int g0 = bid, g1 = bid + NB, g2 = bid + 2 * NB, g3 = bid + 3 * NB;

    // prologue: stage group0 + its boxes (8 VMEM, uniform across waves)
    stage_group(outputs + (size_t)g0 * GRPF, s_buf[0], tid, wave);
    float4 bxA = bx4[(size_t)g0 * 16 + lane];
    int    labA = labels[(size_t)g0 * 16 + lane] - 1;

    float acc = 0.0f;

    // ---- it 0: prefetch g1 -> buf1, compute g0 in buf0 ----
    stage_group(outputs + (size_t)g1 * GRPF, s_buf[1], tid, wave);
    float4 bxB = bx4[(size_t)g1 * 16 + lane];
    int    labB = labels[(size_t)g1 * 16 + lane] - 1;
    WAIT_VM8();
    acc += compute_group(s_buf[0], s_ns, bxA, labA, wave, lane);
    END_BAR();

    // ---- it 1: prefetch g2 -> buf0, compute g1 in buf1 ----
    stage_group(outputs + (size_t)g2 * GRPF, s_buf[0], tid, wave);
    bxA  = bx4[(size_t)g2 * 16 + lane];
    labA = labels[(size_t)g2 * 16 + lane] - 1;
    WAIT_VM8();
    acc += compute_group(s_buf[1], s_ns, bxB, labB, wave, lane);
    END_BAR();

    // ---- it 2: prefetch g3 -> buf1, compute g2 in buf0 ----
    stage_group(outputs + (size_t)g3 * GRPF, s_buf[1], tid, wave);
    bxB  = bx4[(size_t)g3 * 16 + lane];
    labB = labels[(size_t)g3 * 16 + lane] - 1;
    WAIT_VM8();
    acc += compute_group(s_buf[0], s_ns, bxA, labA, wave, lane);
    END_BAR();

    // ---- it 3: compute g3 in buf1 ----
    WAIT_VM0();
    acc += compute_group(s_buf[1], s_ns, bxB, labB, wave, lane);

    if (wave == 0 && lane == 0) block_sum[bid] = acc;
}

__global__ __launch_bounds__(256) void reduce_mean_kernel(
    const float* __restrict__ block_sum, float* __restrict__ out, int nb, int N)
{
    __shared__ double sd[4];
    double acc = 0.0;
    const float4* p4 = reinterpret_cast<const float4*>(block_sum);
    for (int i = threadIdx.x; i < nb / 4; i += 256) {
        float4 v = p4[i];
        acc += (double)v.x + (double)v.y + (double)v.z + (double)v.w;
    }
    #pragma unroll
    for (int off = 32; off > 0; off >>= 1) acc += __shfl_xor(acc, off);
    if ((threadIdx.x & 63) == 0) sd[threadIdx.x >> 6] = acc;
    __syncthreads();
    if (threadIdx.x == 0)
        out[0] = (float)(((sd[0] + sd[1]) + (sd[2] + sd[3])) / (double)N);
}

extern "C" void kernel_launch(void* const* d_in, const int* in_sizes, int n_in,
                              void* d_out, int out_size, void* d_ws, size_t ws_size,
                              hipStream_t stream) {
    const float* outputs = (const float*)d_in[0];
    const float* boxes   = (const float*)d_in[1];
    const int*   labels  = (const int*)d_in[2];
    float* out = (float*)d_out;

    const int N = in_sizes[0] / IMGF;   // 16384 (NB*4 groups * IPB images)
    float* block_sum = (float*)d_ws;    // NB floats

    yolo_loss_kernel<<<NB, 256, 0, stream>>>(outputs, boxes, labels, block_sum);
    reduce_mean_kernel<<<1, 256, 0, stream>>>(block_sum, out, NB, N);
}

// Round 8
// 27.865 us; speedup vs baseline: 3.3487x; 1.0826x over previous
//
#include <hip/hip_runtime.h>

#define Cnum 20
#define NCH  30             // 2*5 + 20
#define NCONF 98
#define IMGF 1470           // floats per image
#define LCf 5.0f
#define LNf 0.5f

// One wave = one image. No LDS, no barriers. 4 lanes per target.
__global__ __launch_bounds__(256) void yolo_loss_kernel(
    const float* __restrict__ outputs,
    const float* __restrict__ boxes,
    const int*   __restrict__ labels,
    float*       __restrict__ per_img)
{
    const int tid  = threadIdx.x;
    const int wave = tid >> 6;
    const int lane = tid & 63;
    const int n    = blockIdx.x * 4 + wave;
    const int t    = lane >> 2;      // target 0..15
    const int q    = lane & 3;       // sub-lane role

    const float* img = outputs + (size_t)n * IMGF;

    // ---- target box + label (4 lanes of a quad load the same -> broadcast) ----
    const float4 bx = reinterpret_cast<const float4*>(boxes)[(size_t)n * 16 + t];
    const int   lab = labels[(size_t)n * 16 + t] - 1;

    const float tx = bx.x, ty = bx.y, tw = bx.z, th = bx.w;
    const float fx = tx * 7.0f, fy = ty * 7.0f;
    const int gxi = (int)fx, gyi = (int)fy;
    const float offx = fx - (float)gxi;
    const float offy = fy - (float)gyi;
    const int cellIdx = gyi * 7 + gxi;
    const float* cell = img + cellIdx * NCH;

    // ---- no-obj conf gather: slot = lane, slot2 = lane+64 (all lanes) ----
    float ns;
    {
        int c = lane >> 1, b = lane & 1;
        float cf = img[c * NCH + b * 5 + 4];
        ns = cf * cf;
        if (lane < NCONF - 64) {
            int s2 = lane + 64;
            int c2 = s2 >> 1, b2 = s2 & 1;
            float cf2 = img[c2 * NCH + b2 * 5 + 4];
            ns += cf2 * cf2;
        }
    }

    // ---- bbox channel loads: q0 -> f0..7, q1 -> f8,f9 ----
    float f[8] = {0.f, 0.f, 0.f, 0.f, 0.f, 0.f, 0.f, 0.f};
    if (q == 0) {
        #pragma unroll
        for (int i = 0; i < 8; ++i) f[i] = cell[i];
    } else if (q == 1) {
        f[0] = cell[8];   // box1.h
        f[1] = cell[9];   // box1.conf
    }
    // pass box1 x,y,w from q0 to q1 (xor-1 pairs q0<->q1, q2<->q3 junk)
    const float e5 = __shfl_xor(f[5], 1);
    const float e6 = __shfl_xor(f[6], 1);
    const float e7 = __shfl_xor(f[7], 1);

    // ---- each of q0,q1 computes its own box's IOU ----
    float px = 0.f, py = 0.f, pw = 0.f, ph = 0.f, pc = 0.f, iou_own = 0.f;
    if (q < 2) {
        float rx = (q == 0) ? f[0] : e5;
        float ry = (q == 0) ? f[1] : e6;
        pw       = (q == 0) ? f[2] : e7;
        ph       = (q == 0) ? f[3] : f[0];
        pc       = (q == 0) ? f[4] : f[1];
        px = (rx + (float)gxi) * (1.0f / 7.0f);
        py = (ry + (float)gyi) * (1.0f / 7.0f);

        float x1a = tx - tw * 0.5f, y1a = ty - th * 0.5f;
        float x2a = tx + tw * 0.5f, y2a = ty + th * 0.5f;
        float x1b = px - pw * 0.5f, y1b = py - ph * 0.5f;
        float x2b = px + pw * 0.5f, y2b = py + ph * 0.5f;
        float iw = fmaxf(fminf(x2a, x2b) - fmaxf(x1a, x1b), 0.0f);
        float ih = fmaxf(fminf(y2a, y2b) - fmaxf(y1a, y1b), 0.0f);
        float inter = iw * ih;
        float uni = tw * th + pw * ph - inter;
        iou_own = inter / fmaxf(uni, 1e-10f);
    }
    const float iou_other = __shfl_xor(iou_own, 1);
    // best = (iou1 >= iou0) ? 1 : 0  (ties -> last box, ref semantics)
    int bestq = 0;
    if (q < 2) {
        float i0 = (q == 0) ? iou_own   : iou_other;
        float i1 = (q == 0) ? iou_other : iou_own;
        bestq = (i1 >= i0) ? 1 : 0;
    }
    const int best = __shfl(bestq, lane & ~3);   // broadcast from quad's q0
    const int s = cellIdx * 2 + best;            // marked slot id (all lanes)

    // ---- box + obj loss on the owning lane ----
    float contrib = 0.0f;
    const float eps = 1e-6f;
    if (q == best) {
        float dx = px - offx, dy = py - offy;
        float dw = sqrtf(fmaxf(pw, eps)) - sqrtf(fmaxf(tw, eps));
        float dh = sqrtf(fmaxf(ph, eps)) - sqrtf(fmaxf(th, eps));
        float box_l = dx * dx + dy * dy + dw * dw + dh * dh;
        float obj_l = (pc - 1.0f) * (pc - 1.0f);
        contrib = LCf * box_l + obj_l;
    }

    // ---- distinct-marked-slot dedup across the 16 targets ----
    bool firstv = true;
    #pragma unroll
    for (int j = 0; j < 15; ++j) {
        int sj = __shfl(s, 4 * j);
        if (j < t && sj == s) firstv = false;
    }
    float ms = 0.0f, mc = 0.0f;
    if (q == best && firstv) { ms = pc * pc; mc = 1.0f; }

    // ---- class loss: 5 classes per lane, quad reductions ----
    {
        float cv[5];
        #pragma unroll
        for (int i = 0; i < 5; ++i) cv[i] = cell[10 + q * 5 + i];
        float m = fmaxf(fmaxf(fmaxf(cv[0], cv[1]), fmaxf(cv[2], cv[3])), cv[4]);
        m = fmaxf(m, __shfl_xor(m, 1));
        m = fmaxf(m, __shfl_xor(m, 2));
        float esum = 0.f, e2 = 0.f, elab = 0.f;
        #pragma unroll
        for (int i = 0; i < 5; ++i) {
            float e = __expf(cv[i] - m);
            esum += e; e2 += e * e;
            if (q * 5 + i == lab) elab = e;
        }
        esum += __shfl_xor(esum, 1);  esum += __shfl_xor(esum, 2);
        e2   += __shfl_xor(e2,   1);  e2   += __shfl_xor(e2,   2);
        elab += __shfl_xor(elab, 1);  elab += __shfl_xor(elab, 2);
        if (q == 0) {
            float inv = 1.0f / esum;
            contrib += e2 * inv * inv - 2.0f * elab * inv + 1.0f;
        }
    }

    // ---- 64-lane reduce of {contrib, ms, mc, ns} ----
    #pragma unroll
    for (int off = 32; off > 0; off >>= 1) {
        contrib += __shfl_xor(contrib, off);
        ms      += __shfl_xor(ms,      off);
        mc      += __shfl_xor(mc,      off);
        ns      += __shfl_xor(ns,      off);
    }
    if (lane == 0)
        per_img[n] = contrib + LNf * (ns - ms) / (98.0f - mc);
}

__global__ __launch_bounds__(1024) void reduce_mean_kernel(
    const float* __restrict__ per_img, float* __restrict__ out, int N)
{
    __shared__ double sd[16];
    double acc = 0.0;
    const float4* p4 = reinterpret_cast<const float4*>(per_img);
    for (int i = threadIdx.x; i < N / 4; i += 1024) {
        float4 v = p4[i];
        acc += (double)v.x + (double)v.y + (double)v.z + (double)v.w;
    }
    #pragma unroll
    for (int off = 32; off > 0; off >>= 1) acc += __shfl_xor(acc, off);
    if ((threadIdx.x & 63) == 0) sd[threadIdx.x >> 6] = acc;
    __syncthreads();
    if (threadIdx.x == 0) {
        double t = 0.0;
        #pragma unroll
        for (int w = 0; w < 16; ++w) t += sd[w];
        out[0] = (float)(t / (double)N);
    }
}

extern "C" void kernel_launch(void* const* d_in, const int* in_sizes, int n_in,
                              void* d_out, int out_size, void* d_ws, size_t ws_size,
                              hipStream_t stream) {
    const float* outputs = (const float*)d_in[0];
    const float* boxes   = (const float*)d_in[1];
    const int*   labels  = (const int*)d_in[2];
    float* out = (float*)d_out;

    const int N = in_sizes[0] / IMGF;   // 16384 images
    float* per_img = (float*)d_ws;      // N floats

    yolo_loss_kernel<<<N / 4, 256, 0, stream>>>(outputs, boxes, labels, per_img);
    reduce_mean_kernel<<<1, 1024, 0, stream>>>(per_img, out, N);
}

// Round 9
// 25.836 us; speedup vs baseline: 3.6116x; 1.0785x over previous
//
#include <hip/hip_runtime.h>

#define Cnum 20
#define NCH  30             // 2*5 + 20
#define NCONF 98
#define IMGF 1470           // floats per image
#define IPB  4              // images per block, one wave each
#define LCf 5.0f
#define LNf 0.5f

// Round-4 staging (coalesced global_load_lds) + round-8 dense quad compute.
// One barrier total; each wave owns one image end-to-end.
__global__ __launch_bounds__(256) void yolo_loss_kernel(
    const float* __restrict__ outputs,
    const float* __restrict__ boxes,
    const int*   __restrict__ labels,
    float*       __restrict__ per_img)
{
    const int tid  = threadIdx.x;
    const int wave = tid >> 6;
    const int lane = tid & 63;
    const int n0   = blockIdx.x * IPB;
    const int n    = n0 + wave;
    const int t    = lane >> 2;      // target 0..15
    const int q    = lane & 3;       // quad role

    __shared__ float s_all[IPB * IMGF];   // 23520 B

    // ---- stage 4 images into LDS: 1470 float4 via width-16 global_load_lds ----
    const float* gsrc = outputs + (size_t)n0 * IMGF;
    #pragma unroll
    for (int k = 0; k < 6; ++k) {
        int j = tid + k * 256;                       // float4 index
        if (j < (IPB * IMGF) / 4) {                  // 1470
            __builtin_amdgcn_global_load_lds(
                (const __attribute__((address_space(1))) void*)(gsrc + (size_t)j * 4),
                (__attribute__((address_space(3))) void*)((char*)s_all + (size_t)(k * 256 + wave * 64) * 16),
                16, 0, 0);
        }
    }

    // hoist target-data loads above the barrier (latency hides under staging)
    const float4 bx = reinterpret_cast<const float4*>(boxes)[(size_t)n * 16 + t];
    const int   lab = labels[(size_t)n * 16 + t] - 1;

    __syncthreads();   // the only barrier

    const float* img = s_all + wave * IMGF;

    const float tx = bx.x, ty = bx.y, tw = bx.z, th = bx.w;
    const float fx = tx * 7.0f, fy = ty * 7.0f;
    const int gxi = (int)fx, gyi = (int)fy;
    const float offx = fx - (float)gxi;
    const float offy = fy - (float)gyi;
    const int cellIdx = gyi * 7 + gxi;
    const float* cell = img + cellIdx * NCH;

    // ---- no-obj conf^2 sum: slots lane and lane+64 (from LDS) ----
    float ns;
    {
        int c = lane >> 1, b = lane & 1;
        float cf = img[c * NCH + b * 5 + 4];
        ns = cf * cf;
        if (lane < NCONF - 64) {
            int s2 = lane + 64;
            int c2 = s2 >> 1, b2 = s2 & 1;
            float cf2 = img[c2 * NCH + b2 * 5 + 4];
            ns += cf2 * cf2;
        }
    }

    // ---- q0/q1 each read their own box's 5 floats from LDS and compute IOU ----
    float px = 0.f, py = 0.f, pw = 0.f, ph = 0.f, pc = 0.f, iou_own = 0.f;
    if (q < 2) {
        float rx = cell[q * 5 + 0];
        float ry = cell[q * 5 + 1];
        pw       = cell[q * 5 + 2];
        ph       = cell[q * 5 + 3];
        pc       = cell[q * 5 + 4];
        px = (rx + (float)gxi) * (1.0f / 7.0f);
        py = (ry + (float)gyi) * (1.0f / 7.0f);

        float x1a = tx - tw * 0.5f, y1a = ty - th * 0.5f;
        float x2a = tx + tw * 0.5f, y2a = ty + th * 0.5f;
        float x1b = px - pw * 0.5f, y1b = py - ph * 0.5f;
        float x2b = px + pw * 0.5f, y2b = py + ph * 0.5f;
        float iw = fmaxf(fminf(x2a, x2b) - fmaxf(x1a, x1b), 0.0f);
        float ih = fmaxf(fminf(y2a, y2b) - fmaxf(y1a, y1b), 0.0f);
        float inter = iw * ih;
        float uni = tw * th + pw * ph - inter;
        iou_own = inter / fmaxf(uni, 1e-10f);
    }
    const float iou_other = __shfl_xor(iou_own, 1);
    int bestq = 0;
    if (q < 2) {
        float i0 = (q == 0) ? iou_own   : iou_other;
        float i1 = (q == 0) ? iou_other : iou_own;
        bestq = (i1 >= i0) ? 1 : 0;      // ties -> last box (ref semantics)
    }
    const int best = __shfl(bestq, lane & ~3);    // broadcast from quad's q0
    const int s = cellIdx * 2 + best;             // marked slot id

    // ---- box + obj loss on the owning lane ----
    float contrib = 0.0f;
    const float eps = 1e-6f;
    if (q == best) {
        float dx = px - offx, dy = py - offy;
        float dw = sqrtf(fmaxf(pw, eps)) - sqrtf(fmaxf(tw, eps));
        float dh = sqrtf(fmaxf(ph, eps)) - sqrtf(fmaxf(th, eps));
        float box_l = dx * dx + dy * dy + dw * dw + dh * dh;
        float obj_l = (pc - 1.0f) * (pc - 1.0f);
        contrib = LCf * box_l + obj_l;
    }

    // ---- distinct-marked-slot dedup across the 16 targets ----
    bool firstv = true;
    #pragma unroll
    for (int j = 0; j < 15; ++j) {
        int sj = __shfl(s, 4 * j);
        if (j < t && sj == s) firstv = false;
    }
    float ms = 0.0f, mc = 0.0f;
    if (q == best && firstv) { ms = pc * pc; mc = 1.0f; }

    // ---- class loss: 5 classes per lane, quad reductions ----
    {
        float cv[5];
        #pragma unroll
        for (int i = 0; i < 5; ++i) cv[i] = cell[10 + q * 5 + i];
        float m = fmaxf(fmaxf(fmaxf(cv[0], cv[1]), fmaxf(cv[2], cv[3])), cv[4]);
        m = fmaxf(m, __shfl_xor(m, 1));
        m = fmaxf(m, __shfl_xor(m, 2));
        float esum = 0.f, e2 = 0.f, elab = 0.f;
        #pragma unroll
        for (int i = 0; i < 5; ++i) {
            float e = __expf(cv[i] - m);
            esum += e; e2 += e * e;
            if (q * 5 + i == lab) elab = e;
        }
        esum += __shfl_xor(esum, 1);  esum += __shfl_xor(esum, 2);
        e2   += __shfl_xor(e2,   1);  e2   += __shfl_xor(e2,   2);
        elab += __shfl_xor(elab, 1);  elab += __shfl_xor(elab, 2);
        if (q == 0) {
            float inv = 1.0f / esum;
            contrib += e2 * inv * inv - 2.0f * elab * inv + 1.0f;
        }
    }

    // ---- 64-lane reduce of {contrib, ms, mc, ns}; lane 0 writes ----
    #pragma unroll
    for (int off = 32; off > 0; off >>= 1) {
        contrib += __shfl_xor(contrib, off);
        ms      += __shfl_xor(ms,      off);
        mc      += __shfl_xor(mc,      off);
        ns      += __shfl_xor(ns,      off);
    }
    if (lane == 0)
        per_img[n] = contrib + LNf * (ns - ms) / (98.0f - mc);
}

__global__ __launch_bounds__(1024) void reduce_mean_kernel(
    const float* __restrict__ per_img, float* __restrict__ out, int N)
{
    __shared__ double sd[16];
    double acc = 0.0;
    const float4* p4 = reinterpret_cast<const float4*>(per_img);
    for (int i = threadIdx.x; i < N / 4; i += 1024) {
        float4 v = p4[i];
        acc += (double)v.x + (double)v.y + (double)v.z + (double)v.w;
    }
    #pragma unroll
    for (int off = 32; off > 0; off >>= 1) acc += __shfl_xor(acc, off);
    if ((threadIdx.x & 63) == 0) sd[threadIdx.x >> 6] = acc;
    __syncthreads();
    if (threadIdx.x == 0) {
        double t = 0.0;
        #pragma unroll
        for (int w = 0; w < 16; ++w) t += sd[w];
        out[0] = (float)(t / (double)N);
    }
}

extern "C" void kernel_launch(void* const* d_in, const int* in_sizes, int n_in,
                              void* d_out, int out_size, void* d_ws, size_t ws_size,
                              hipStream_t stream) {
    const float* outputs = (const float*)d_in[0];
    const float* boxes   = (const float*)d_in[1];
    const int*   labels  = (const int*)d_in[2];
    float* out = (float*)d_out;

    const int N = in_sizes[0] / IMGF;   // 16384 images
    float* per_img = (float*)d_ws;      // N floats

    yolo_loss_kernel<<<N / IPB, 256, 0, stream>>>(outputs, boxes, labels, per_img);
    reduce_mean_kernel<<<1, 1024, 0, stream>>>(per_img, out, N);
}